// Round 1
// baseline (7741.486 us; speedup 1.0000x reference)
//
#include <hip/hip_runtime.h>
#include <hip/hip_bf16.h>

#define H 128
#define FEAT 7
#define ROWS 16

__device__ __forceinline__ float conv3(float x, float w, float b) {
    x = fmaxf(fmaf(w, x, b), 0.f);
    x = fmaxf(fmaf(w, x, b), 0.f);
    x = fmaxf(fmaf(w, x, b), 0.f);
    return x;
}

// Leaf level: emb = conv3(contents @ W_u + b_u)
__global__ __launch_bounds__(256) void leaf_kernel(
    const float* __restrict__ contents,   // pre-offset to level-9 rows, (n,7)
    const float* __restrict__ Wu,         // (7,128)
    const float* __restrict__ bu,         // (128,)
    const float* __restrict__ convw, const float* __restrict__ convb,
    __hip_bfloat16* __restrict__ emb,     // (n,128)
    int n)
{
    int idx = blockIdx.x * blockDim.x + threadIdx.x;
    if (idx >= n * H) return;
    int row = idx >> 7, h = idx & 127;
    const float* c = contents + row * FEAT;
    float acc = bu[h];
#pragma unroll
    for (int k = 0; k < FEAT; k++) acc = fmaf(c[k], Wu[k * H + h], acc);
    emb[idx] = __float2bfloat16(conv3(acc, convw[0], convb[0]));
}

// Fused non-leaf level. 16 rows per block of 256 threads.
__global__ __launch_bounds__(256, 2) void level_kernel(
    const float* __restrict__ contents,   // pre-offset, (n,7)
    const int* __restrict__ children,     // pre-offset, (n,2)
    const __hip_bfloat16* __restrict__ embPrev,  // (2n,128)
    __hip_bfloat16* __restrict__ embOut,         // (n,128)
    float* __restrict__ finalOut,                // non-null only at level 0
    const float* __restrict__ Wu, const float* __restrict__ bu,
    const float* __restrict__ Wh, const float* __restrict__ bh,
    const float* __restrict__ Wz, const float* __restrict__ bz,
    const float* __restrict__ Wr, const float* __restrict__ br,
    const float* __restrict__ convw, const float* __restrict__ convb,
    int n)
{
    __shared__ float s_hhu[ROWS][384];   // [h_L | h_R | u]
    __shared__ float s_x[ROWS][384];     // r * hhu
    __shared__ float s_hH[ROWS][H];

    const int t = threadIdx.x;
    const int row0 = blockIdx.x * ROWS;
    const float cw = convw[0], cb = convb[0];

    // ---- Stage A: u = conv3(c @ Wu + bu) -> s_hhu[:, 256:384]
#pragma unroll
    for (int i = 0; i < 8; i++) {
        int o = t + i * 256;          // 0..2047
        int r = o >> 7, h = o & 127;
        const float* c = contents + (row0 + r) * FEAT;
        float acc = bu[h];
#pragma unroll
        for (int k = 0; k < FEAT; k++) acc = fmaf(c[k], Wu[k * H + h], acc);
        s_hhu[r][256 + h] = conv3(acc, cw, cb);
    }

    // ---- Stage B: gather h_L, h_R from previous level
#pragma unroll 4
    for (int r = 0; r < ROWS; r++) {
        int child = children[(row0 + r) * 2 + (t >> 7)];
        s_hhu[r][t] = __bfloat162float(embPrev[child * H + (t & 127)]);
    }
    __syncthreads();

    const int col = t & 127;
    const int rbase = (t >> 7) << 3;   // 0 or 8

    // ---- Stage C: r = sigmoid(hhu @ Wr + br); x = r * hhu
    {
        float a0[8], a1[8], a2[8];
#pragma unroll
        for (int r = 0; r < 8; r++) { a0[r] = 0.f; a1[r] = 0.f; a2[r] = 0.f; }
        const float* wr = Wr + col;
#pragma unroll 4
        for (int k = 0; k < 384; k++) {
            float w0 = wr[k * 384];
            float w1 = wr[k * 384 + 128];
            float w2 = wr[k * 384 + 256];
#pragma unroll
            for (int r = 0; r < 8; r++) {
                float a = s_hhu[rbase + r][k];
                a0[r] = fmaf(a, w0, a0[r]);
                a1[r] = fmaf(a, w1, a1[r]);
                a2[r] = fmaf(a, w2, a2[r]);
            }
        }
        float b0 = br[col], b1 = br[128 + col], b2 = br[256 + col];
#pragma unroll
        for (int r = 0; r < 8; r++) {
            int rr = rbase + r;
            float r0 = 1.f / (1.f + __expf(-(a0[r] + b0)));
            float r1 = 1.f / (1.f + __expf(-(a1[r] + b1)));
            float r2 = 1.f / (1.f + __expf(-(a2[r] + b2)));
            s_x[rr][col]       = r0 * s_hhu[rr][col];
            s_x[rr][128 + col] = r1 * s_hhu[rr][128 + col];
            s_x[rr][256 + col] = r2 * s_hhu[rr][256 + col];
        }
    }
    __syncthreads();

    // ---- Stage D: h_H = conv3(x @ Wh + bh)
    {
        float acc[8];
#pragma unroll
        for (int r = 0; r < 8; r++) acc[r] = 0.f;
        const float* wh = Wh + col;
#pragma unroll 4
        for (int k = 0; k < 384; k++) {
            float w = wh[k * H];
#pragma unroll
            for (int r = 0; r < 8; r++)
                acc[r] = fmaf(s_x[rbase + r][k], w, acc[r]);
        }
        float bb = bh[col];
#pragma unroll
        for (int r = 0; r < 8; r++)
            s_hH[rbase + r][col] = conv3(acc[r] + bb, cw, cb);
    }
    __syncthreads();

    // ---- Stage E: z = [h_H, hhu] @ Wz + bz ; 4-way softmax gate ; emb out
    {
        float a0[8], a1[8], a2[8], a3[8];
#pragma unroll
        for (int r = 0; r < 8; r++) { a0[r] = 0.f; a1[r] = 0.f; a2[r] = 0.f; a3[r] = 0.f; }
        const float* wz = Wz + col;
#pragma unroll 4
        for (int k = 0; k < 128; k++) {   // K-part from h_H
            float w0 = wz[k * 512];
            float w1 = wz[k * 512 + 128];
            float w2 = wz[k * 512 + 256];
            float w3 = wz[k * 512 + 384];
#pragma unroll
            for (int r = 0; r < 8; r++) {
                float a = s_hH[rbase + r][k];
                a0[r] = fmaf(a, w0, a0[r]);
                a1[r] = fmaf(a, w1, a1[r]);
                a2[r] = fmaf(a, w2, a2[r]);
                a3[r] = fmaf(a, w3, a3[r]);
            }
        }
#pragma unroll 4
        for (int k = 0; k < 384; k++) {   // K-part from hhu
            const float* wzk = wz + (k + 128) * 512;
            float w0 = wzk[0];
            float w1 = wzk[128];
            float w2 = wzk[256];
            float w3 = wzk[384];
#pragma unroll
            for (int r = 0; r < 8; r++) {
                float a = s_hhu[rbase + r][k];
                a0[r] = fmaf(a, w0, a0[r]);
                a1[r] = fmaf(a, w1, a1[r]);
                a2[r] = fmaf(a, w2, a2[r]);
                a3[r] = fmaf(a, w3, a3[r]);
            }
        }
        float bz0 = bz[col], bz1 = bz[128 + col], bz2 = bz[256 + col], bz3 = bz[384 + col];
#pragma unroll
        for (int r = 0; r < 8; r++) {
            int rr = rbase + r;
            float z0 = a0[r] + bz0, z1 = a1[r] + bz1, z2 = a2[r] + bz2, z3 = a3[r] + bz3;
            float m = fmaxf(fmaxf(z0, z1), fmaxf(z2, z3));
            float e0 = __expf(z0 - m), e1 = __expf(z1 - m), e2 = __expf(z2 - m), e3 = __expf(z3 - m);
            float inv = 1.f / (e0 + e1 + e2 + e3);
            float hH = s_hH[rr][col];
            float hL = s_hhu[rr][col];
            float hR = s_hhu[rr][128 + col];
            float uu = s_hhu[rr][256 + col];
            float e = (e0 * hH + e1 * hL + e2 * hR + e3 * uu) * inv;
            int gidx = (row0 + rr) * H + col;
            if (finalOut) finalOut[gidx] = e;
            else embOut[gidx] = __float2bfloat16(e);
        }
    }
}

extern "C" void kernel_launch(void* const* d_in, const int* in_sizes, int n_in,
                              void* d_out, int out_size, void* d_ws, size_t ws_size,
                              hipStream_t stream) {
    const float* contents = (const float*)d_in[0];
    const int*   children = (const int*)d_in[1];
    const float* Wu = (const float*)d_in[2];
    const float* bu = (const float*)d_in[3];
    const float* Wh = (const float*)d_in[4];
    const float* bh = (const float*)d_in[5];
    const float* Wz = (const float*)d_in[6];
    const float* bz = (const float*)d_in[7];
    const float* Wr = (const float*)d_in[8];
    const float* br = (const float*)d_in[9];
    const float* convw = (const float*)d_in[10];
    const float* convb = (const float*)d_in[11];
    float* out = (float*)d_out;

    // emb ping-pong in workspace, bf16.
    // bufA holds odd-parity levels (9,7,5,...) max 524288*128 elems = 128 MB
    // bufB holds even-parity levels (8,6,...) max 262144*128 elems = 64 MB
    __hip_bfloat16* bufA = (__hip_bfloat16*)d_ws;
    __hip_bfloat16* bufB = bufA + (size_t)524288 * H;

    // OFF[j] = COFF[j] = 1024*(2^j - 1)
    auto OFFS = [](int j) -> long long { return 1024LL * ((1LL << j) - 1); };

    // Level 9 (leaf): n = 524288
    {
        int n = 1024 << 9;
        int total = n * H;
        leaf_kernel<<<(total + 255) / 256, 256, 0, stream>>>(
            contents + OFFS(9) * FEAT, Wu, bu, convw, convb, bufA, n);
    }

    __hip_bfloat16* prev = bufA;
    __hip_bfloat16* cur  = bufB;
    for (int j = 8; j >= 0; j--) {
        int n = 1024 << j;
        level_kernel<<<n / ROWS, 256, 0, stream>>>(
            contents + OFFS(j) * FEAT,
            children + OFFS(j) * 2,
            prev, cur, (j == 0 ? out : nullptr),
            Wu, bu, Wh, bh, Wz, bz, Wr, br, convw, convb, n);
        __hip_bfloat16* tmp = prev; prev = cur; cur = tmp;
    }
}

// Round 2
// 1066.582 us; speedup vs baseline: 7.2582x; 7.2582x over previous
//
#include <hip/hip_runtime.h>
#include <hip/hip_bf16.h>

typedef _Float16 f16x8 __attribute__((ext_vector_type(8)));
typedef float f32x4 __attribute__((ext_vector_type(4)));

#define H 128
#define FEAT 7
#define ROWS 32

__device__ __forceinline__ float conv3(float x, float w, float b) {
    x = fmaxf(fmaf(w, x, b), 0.f);
    x = fmaxf(fmaf(w, x, b), 0.f);
    x = fmaxf(fmaf(w, x, b), 0.f);
    return x;
}
__device__ __forceinline__ float sigm(float x) { return 1.f / (1.f + __expf(-x)); }

// Pack fp32 row-major W[k][n] -> f16 MFMA-B-fragment layout: P[((k>>3)*N + n)*8 + (k&7)]
__global__ __launch_bounds__(256) void pack_weights(
    const float* __restrict__ Wr, const float* __restrict__ Wh, const float* __restrict__ Wz,
    _Float16* __restrict__ Pr, _Float16* __restrict__ Ph, _Float16* __restrict__ Pz)
{
    int idx = blockIdx.x * 256 + threadIdx.x;
    if (idx < 384 * 384) {
        int k = idx / 384, n = idx % 384;
        Pr[((size_t)(k >> 3) * 384 + n) * 8 + (k & 7)] = (_Float16)Wr[idx];
    }
    if (idx < 384 * 128) {
        int k = idx / 128, n = idx % 128;
        Ph[((size_t)(k >> 3) * 128 + n) * 8 + (k & 7)] = (_Float16)Wh[idx];
    }
    if (idx < 512 * 512) {
        int k = idx / 512, n = idx % 512;
        Pz[((size_t)(k >> 3) * 512 + n) * 8 + (k & 7)] = (_Float16)Wz[idx];
    }
}

// Leaf: emb = conv3(contents @ Wu + bu), f16 out
__global__ __launch_bounds__(256) void leaf_kernel(
    const float* __restrict__ contents,
    const float* __restrict__ Wu, const float* __restrict__ bu,
    const float* __restrict__ convw, const float* __restrict__ convb,
    _Float16* __restrict__ emb, int n)
{
    int idx = blockIdx.x * blockDim.x + threadIdx.x;
    if (idx >= n * H) return;
    int row = idx >> 7, h = idx & 127;
    const float* c = contents + (size_t)row * FEAT;
    float acc = bu[h];
#pragma unroll
    for (int k = 0; k < FEAT; k++) acc = fmaf(c[k], Wu[k * H + h], acc);
    emb[idx] = (_Float16)conv3(acc, convw[0], convb[0]);
}

// Fused non-leaf level, MFMA f16. 32 rows per block of 256 threads (4 waves).
__global__ __launch_bounds__(256, 2) void level_kernel(
    const float* __restrict__ contents,   // pre-offset, (n,7)
    const int* __restrict__ children,     // pre-offset, (n,2)
    const _Float16* __restrict__ embPrev,
    _Float16* __restrict__ embOut,
    float* __restrict__ finalOut,         // non-null only at level 0
    const float* __restrict__ Wu, const float* __restrict__ bu,
    const _Float16* __restrict__ Pr, const float* __restrict__ br,
    const _Float16* __restrict__ Ph, const float* __restrict__ bh,
    const _Float16* __restrict__ Pz, const float* __restrict__ bz,
    const float* __restrict__ convw, const float* __restrict__ convb)
{
    // +8 pad keeps 16B alignment for b128 LDS accesses and breaks bank patterns
    __shared__ __align__(16) _Float16 s_hhu[ROWS][392];  // [h_L | h_R | u]
    __shared__ __align__(16) _Float16 s_x[ROWS][392];    // r * hhu
    __shared__ __align__(16) _Float16 s_hH[ROWS][136];

    const int t = threadIdx.x;
    const int row0 = blockIdx.x * ROWS;
    const int lane = t & 63;
    const int w = t >> 6;          // wave 0..3
    const int q = lane >> 4;       // quad 0..3
    const int ln = lane & 15;
    const float cw = convw[0], cb = convb[0];

    // ---- Stage A: u = conv3(c @ Wu + bu) -> s_hhu[:, 256:384]
#pragma unroll
    for (int i = 0; i < 16; i++) {
        int o = t + i * 256;       // 0..4095
        int r = o >> 7, h = o & 127;
        const float* c = contents + (size_t)(row0 + r) * FEAT;
        float acc = bu[h];
#pragma unroll
        for (int k = 0; k < FEAT; k++) acc = fmaf(c[k], Wu[k * H + h], acc);
        s_hhu[r][256 + h] = (_Float16)conv3(acc, cw, cb);
    }

    // ---- Stage B: gather h_L, h_R (16B vector loads)
    {
        int rp = t >> 4, chunk = t & 15;
#pragma unroll
        for (int p = 0; p < 4; p++) {
            int cr = p * 16 + rp;              // child slot 0..63
            int r = cr >> 1, s = cr & 1;
            int child = children[row0 * 2 + cr];
            uint4 v = *(const uint4*)(embPrev + (size_t)child * H + chunk * 8);
            *(uint4*)&s_hhu[r][s * 128 + chunk * 8] = v;
        }
    }
    __syncthreads();

    // ---- Stage C: r = sigmoid(hhu @ Wr + br); x = r * hhu  (N=384, K=384)
    {
        f32x4 acc[6][2];
#pragma unroll
        for (int c = 0; c < 6; c++)
#pragma unroll
            for (int rt = 0; rt < 2; rt++) acc[c][rt] = (f32x4){0.f, 0.f, 0.f, 0.f};
        const f16x8* PB = (const f16x8*)Pr;
        for (int kk = 0; kk < 12; kk++) {
            int k0 = kk * 32;
            f16x8 a0 = *(const f16x8*)&s_hhu[ln][k0 + q * 8];
            f16x8 a1 = *(const f16x8*)&s_hhu[16 + ln][k0 + q * 8];
            int kb = kk * 4 + q;
#pragma unroll
            for (int c = 0; c < 6; c++) {
                f16x8 b = PB[(size_t)kb * 384 + w * 96 + c * 16 + ln];
                acc[c][0] = __builtin_amdgcn_mfma_f32_16x16x32_f16(a0, b, acc[c][0], 0, 0, 0);
                acc[c][1] = __builtin_amdgcn_mfma_f32_16x16x32_f16(a1, b, acc[c][1], 0, 0, 0);
            }
        }
#pragma unroll
        for (int c = 0; c < 6; c++) {
            int colg = w * 96 + c * 16 + ln;
            float bb = br[colg];
#pragma unroll
            for (int rt = 0; rt < 2; rt++)
#pragma unroll
                for (int reg = 0; reg < 4; reg++) {
                    int row = rt * 16 + q * 4 + reg;
                    float rv = sigm(acc[c][rt][reg] + bb);
                    s_x[row][colg] = (_Float16)(rv * (float)s_hhu[row][colg]);
                }
        }
    }
    __syncthreads();

    // ---- Stage D: h_H = conv3(x @ Wh + bh)  (N=128, K=384)
    {
        f32x4 acc[2][2];
#pragma unroll
        for (int c = 0; c < 2; c++)
#pragma unroll
            for (int rt = 0; rt < 2; rt++) acc[c][rt] = (f32x4){0.f, 0.f, 0.f, 0.f};
        const f16x8* PB = (const f16x8*)Ph;
        for (int kk = 0; kk < 12; kk++) {
            int k0 = kk * 32;
            f16x8 a0 = *(const f16x8*)&s_x[ln][k0 + q * 8];
            f16x8 a1 = *(const f16x8*)&s_x[16 + ln][k0 + q * 8];
            int kb = kk * 4 + q;
#pragma unroll
            for (int c = 0; c < 2; c++) {
                f16x8 b = PB[(size_t)kb * 128 + w * 32 + c * 16 + ln];
                acc[c][0] = __builtin_amdgcn_mfma_f32_16x16x32_f16(a0, b, acc[c][0], 0, 0, 0);
                acc[c][1] = __builtin_amdgcn_mfma_f32_16x16x32_f16(a1, b, acc[c][1], 0, 0, 0);
            }
        }
#pragma unroll
        for (int c = 0; c < 2; c++) {
            int colg = w * 32 + c * 16 + ln;
            float bb = bh[colg];
#pragma unroll
            for (int rt = 0; rt < 2; rt++)
#pragma unroll
                for (int reg = 0; reg < 4; reg++) {
                    int row = rt * 16 + q * 4 + reg;
                    s_hH[row][colg] = (_Float16)conv3(acc[c][rt][reg] + bb, cw, cb);
                }
        }
    }
    __syncthreads();

    // ---- Stage E: z = [h_H | hhu] @ Wz + bz; softmax gate; write out (N=512, K=512)
    const f16x8* PBz = (const f16x8*)Pz;
#pragma unroll
    for (int sub = 0; sub < 32; sub += 16) {
        f32x4 acc[4][2];
#pragma unroll
        for (int q4 = 0; q4 < 4; q4++)
#pragma unroll
            for (int rt = 0; rt < 2; rt++) acc[q4][rt] = (f32x4){0.f, 0.f, 0.f, 0.f};
        int nc = w * 32 + sub;  // col-tile base within each 128-col quarter
        // K part 1: h_H (k 0..127)
        for (int kk = 0; kk < 4; kk++) {
            int k0 = kk * 32;
            f16x8 a0 = *(const f16x8*)&s_hH[ln][k0 + q * 8];
            f16x8 a1 = *(const f16x8*)&s_hH[16 + ln][k0 + q * 8];
            int kb = kk * 4 + q;
#pragma unroll
            for (int q4 = 0; q4 < 4; q4++) {
                f16x8 b = PBz[(size_t)kb * 512 + q4 * 128 + nc + ln];
                acc[q4][0] = __builtin_amdgcn_mfma_f32_16x16x32_f16(a0, b, acc[q4][0], 0, 0, 0);
                acc[q4][1] = __builtin_amdgcn_mfma_f32_16x16x32_f16(a1, b, acc[q4][1], 0, 0, 0);
            }
        }
        // K part 2: hhu (k 128..511)
        for (int kk = 4; kk < 16; kk++) {
            int k0 = kk * 32 - 128;
            f16x8 a0 = *(const f16x8*)&s_hhu[ln][k0 + q * 8];
            f16x8 a1 = *(const f16x8*)&s_hhu[16 + ln][k0 + q * 8];
            int kb = kk * 4 + q;
#pragma unroll
            for (int q4 = 0; q4 < 4; q4++) {
                f16x8 b = PBz[(size_t)kb * 512 + q4 * 128 + nc + ln];
                acc[q4][0] = __builtin_amdgcn_mfma_f32_16x16x32_f16(a0, b, acc[q4][0], 0, 0, 0);
                acc[q4][1] = __builtin_amdgcn_mfma_f32_16x16x32_f16(a1, b, acc[q4][1], 0, 0, 0);
            }
        }
        int colg = nc + ln;  // 0..127
        float b0 = bz[colg], b1 = bz[128 + colg], b2 = bz[256 + colg], b3 = bz[384 + colg];
#pragma unroll
        for (int rt = 0; rt < 2; rt++)
#pragma unroll
            for (int reg = 0; reg < 4; reg++) {
                int row = rt * 16 + q * 4 + reg;
                float z0 = acc[0][rt][reg] + b0;
                float z1 = acc[1][rt][reg] + b1;
                float z2 = acc[2][rt][reg] + b2;
                float z3 = acc[3][rt][reg] + b3;
                float m = fmaxf(fmaxf(z0, z1), fmaxf(z2, z3));
                float e0 = __expf(z0 - m), e1 = __expf(z1 - m), e2 = __expf(z2 - m), e3 = __expf(z3 - m);
                float inv = 1.f / (e0 + e1 + e2 + e3);
                float hH = (float)s_hH[row][colg];
                float hL = (float)s_hhu[row][colg];
                float hR = (float)s_hhu[row][128 + colg];
                float uu = (float)s_hhu[row][256 + colg];
                float e = (e0 * hH + e1 * hL + e2 * hR + e3 * uu) * inv;
                size_t gidx = (size_t)(row0 + row) * H + colg;
                if (finalOut) finalOut[gidx] = e;
                else embOut[gidx] = (_Float16)e;
            }
    }
}

extern "C" void kernel_launch(void* const* d_in, const int* in_sizes, int n_in,
                              void* d_out, int out_size, void* d_ws, size_t ws_size,
                              hipStream_t stream) {
    const float* contents = (const float*)d_in[0];
    const int*   children = (const int*)d_in[1];
    const float* Wu = (const float*)d_in[2];
    const float* bu = (const float*)d_in[3];
    const float* Wh = (const float*)d_in[4];
    const float* bh = (const float*)d_in[5];
    const float* Wz = (const float*)d_in[6];
    const float* bz = (const float*)d_in[7];
    const float* Wr = (const float*)d_in[8];
    const float* br = (const float*)d_in[9];
    const float* convw = (const float*)d_in[10];
    const float* convb = (const float*)d_in[11];
    float* out = (float*)d_out;

    // Workspace layout: [packed weights ~0.9MB][bufA 128MB][bufB 64MB]
    _Float16* Pr = (_Float16*)d_ws;              // 384*384
    _Float16* Ph = Pr + 384 * 384;               // 384*128
    _Float16* Pz = Ph + 384 * 128;               // 512*512
    _Float16* bufA = (_Float16*)((char*)d_ws + (1 << 20));
    _Float16* bufB = bufA + (size_t)524288 * H;

    auto OFFS = [](int j) -> long long { return 1024LL * ((1LL << j) - 1); };

    pack_weights<<<(512 * 512 + 255) / 256, 256, 0, stream>>>(Wr, Wh, Wz, Pr, Ph, Pz);

    // Level 9 (leaf): n = 524288
    {
        int n = 1024 << 9;
        int total = n * H;
        leaf_kernel<<<(total + 255) / 256, 256, 0, stream>>>(
            contents + OFFS(9) * FEAT, Wu, bu, convw, convb, bufA, n);
    }

    _Float16* prev = bufA;
    _Float16* cur  = bufB;
    for (int j = 8; j >= 0; j--) {
        int n = 1024 << j;
        level_kernel<<<n / ROWS, 256, 0, stream>>>(
            contents + OFFS(j) * FEAT,
            children + OFFS(j) * 2,
            prev, cur, (j == 0 ? out : nullptr),
            Wu, bu, Pr, br, Ph, bh, Pz, bz, convw, convb);
        _Float16* tmp = prev; prev = cur; cur = tmp;
    }
}

// Round 3
// 938.024 us; speedup vs baseline: 8.2530x; 1.1371x over previous
//
#include <hip/hip_runtime.h>
#include <hip/hip_bf16.h>

typedef _Float16 f16x8 __attribute__((ext_vector_type(8)));
typedef float f32x4 __attribute__((ext_vector_type(4)));

#define H 128
#define FEAT 7
#define ROWS 32

__device__ __forceinline__ float conv3(float x, float w, float b) {
    x = fmaxf(fmaf(w, x, b), 0.f);
    x = fmaxf(fmaf(w, x, b), 0.f);
    x = fmaxf(fmaf(w, x, b), 0.f);
    return x;
}
__device__ __forceinline__ float sigm(float x) { return 1.f / (1.f + __expf(-x)); }

// Pack fp32 row-major W[k][n] -> f16 MFMA-B-fragment layout: P[((k>>3)*N + n)*8 + (k&7)]
__global__ __launch_bounds__(256) void pack_weights(
    const float* __restrict__ Wr, const float* __restrict__ Wh, const float* __restrict__ Wz,
    _Float16* __restrict__ Pr, _Float16* __restrict__ Ph, _Float16* __restrict__ Pz)
{
    int idx = blockIdx.x * 256 + threadIdx.x;
    if (idx < 384 * 384) {
        int k = idx / 384, n = idx % 384;
        Pr[((size_t)(k >> 3) * 384 + n) * 8 + (k & 7)] = (_Float16)Wr[idx];
    }
    if (idx < 384 * 128) {
        int k = idx / 128, n = idx % 128;
        Ph[((size_t)(k >> 3) * 128 + n) * 8 + (k & 7)] = (_Float16)Wh[idx];
    }
    if (idx < 512 * 512) {
        int k = idx / 512, n = idx % 512;
        Pz[((size_t)(k >> 3) * 512 + n) * 8 + (k & 7)] = (_Float16)Wz[idx];
    }
}

// Fused level kernel, MFMA f16, 32 rows / 256 threads, depth-1 SW pipeline.
// LEAF=true (j=8): children embeddings computed inline from level-9 contents.
template<bool LEAF>
__global__ __launch_bounds__(256, 3) void level_kernel(
    const float* __restrict__ contents,     // pre-offset, (n,7)
    const int* __restrict__ children,       // pre-offset, (n,2)
    const float* __restrict__ leafContents, // level-9 contents (LEAF only)
    const _Float16* __restrict__ embPrev,   // (!LEAF)
    _Float16* __restrict__ embOut,
    float* __restrict__ finalOut,           // non-null only at level 0
    const float* __restrict__ Wu, const float* __restrict__ bu,
    const _Float16* __restrict__ Pr, const float* __restrict__ br,
    const _Float16* __restrict__ Ph, const float* __restrict__ bh,
    const _Float16* __restrict__ Pz, const float* __restrict__ bz,
    const float* __restrict__ convw, const float* __restrict__ convb)
{
    __shared__ __align__(16) _Float16 s_hhu[ROWS][392];  // [h_L | h_R | u]
    __shared__ __align__(16) _Float16 s_x[ROWS][392];    // r*hhu; later aliased by s_hH
    _Float16 (* const s_hH)[136] = (_Float16 (*)[136])&s_x[0][0];

    const int t = threadIdx.x;
    const int row0 = blockIdx.x * ROWS;
    const int col0 = t & 127;
    const int thalf = t >> 7;
    const float cw = convw[0], cb = convb[0];

    // Wu column for this thread (used by Stage A and the LEAF path)
    float wcol[FEAT];
#pragma unroll
    for (int k = 0; k < FEAT; k++) wcol[k] = Wu[k * H + col0];
    const float bucol = bu[col0];

    // ---- Stage A: u = conv3(c @ Wu + bu) -> s_hhu[:, 256:384]
#pragma unroll 4
    for (int i = 0; i < 16; i++) {
        int r = 2 * i + thalf;
        const float* c = contents + (size_t)(row0 + r) * FEAT;
        float acc = bucol;
#pragma unroll
        for (int k = 0; k < FEAT; k++) acc = fmaf(c[k], wcol[k], acc);
        s_hhu[r][256 + col0] = (_Float16)conv3(acc, cw, cb);
    }

    // ---- Stage B: children embeddings
    if (LEAF) {
#pragma unroll 4
        for (int i = 0; i < 32; i++) {
            int child = children[row0 * 2 + 2 * i + thalf];
            const float* c = leafContents + (size_t)child * FEAT;
            float acc = bucol;
#pragma unroll
            for (int k = 0; k < FEAT; k++) acc = fmaf(c[k], wcol[k], acc);
            s_hhu[i][thalf * 128 + col0] = (_Float16)conv3(acc, cw, cb);
        }
    } else {
        int rp = t >> 4, chunk = t & 15;
#pragma unroll
        for (int p = 0; p < 4; p++) {
            int cr = p * 16 + rp;
            int r = cr >> 1, s = cr & 1;
            int child = children[row0 * 2 + cr];
            uint4 v = *(const uint4*)(embPrev + (size_t)child * H + chunk * 8);
            *(uint4*)&s_hhu[r][s * 128 + chunk * 8] = v;
        }
    }
    __syncthreads();

    const int lane = t & 63;
    const int w = t >> 6;
    const int q = lane >> 4;
    const int ln = lane & 15;

    // ---- Stage C: r = sigmoid(hhu @ Wr + br); x = r * hhu  (N=384, K=384)
    {
        const f16x8* PB = (const f16x8*)Pr + (w * 96 + ln);
        f32x4 acc[6][2];
#pragma unroll
        for (int c = 0; c < 6; c++) { acc[c][0] = (f32x4){0,0,0,0}; acc[c][1] = (f32x4){0,0,0,0}; }
        f16x8 a0 = *(const f16x8*)&s_hhu[ln][q * 8];
        f16x8 a1 = *(const f16x8*)&s_hhu[16 + ln][q * 8];
        f16x8 bn[6];
#pragma unroll
        for (int c = 0; c < 6; c++) bn[c] = PB[(size_t)q * 384 + c * 16];
#pragma unroll
        for (int kk = 0; kk < 12; kk++) {
            f16x8 ca0 = a0, ca1 = a1;
            f16x8 bc[6];
#pragma unroll
            for (int c = 0; c < 6; c++) bc[c] = bn[c];
            if (kk < 11) {
                int kb = (kk + 1) * 4 + q;
#pragma unroll
                for (int c = 0; c < 6; c++) bn[c] = PB[(size_t)kb * 384 + c * 16];
                a0 = *(const f16x8*)&s_hhu[ln][(kk + 1) * 32 + q * 8];
                a1 = *(const f16x8*)&s_hhu[16 + ln][(kk + 1) * 32 + q * 8];
            }
#pragma unroll
            for (int c = 0; c < 6; c++) {
                acc[c][0] = __builtin_amdgcn_mfma_f32_16x16x32_f16(ca0, bc[c], acc[c][0], 0, 0, 0);
                acc[c][1] = __builtin_amdgcn_mfma_f32_16x16x32_f16(ca1, bc[c], acc[c][1], 0, 0, 0);
            }
        }
#pragma unroll
        for (int c = 0; c < 6; c++) {
            int colg = w * 96 + c * 16 + ln;
            float bb = br[colg];
#pragma unroll
            for (int rt = 0; rt < 2; rt++)
#pragma unroll
                for (int reg = 0; reg < 4; reg++) {
                    int row = rt * 16 + q * 4 + reg;
                    float rv = sigm(acc[c][rt][reg] + bb);
                    s_x[row][colg] = (_Float16)(rv * (float)s_hhu[row][colg]);
                }
        }
    }
    __syncthreads();

    // ---- Stage D: h_H = conv3(x @ Wh + bh)  (N=128, K=384); s_hH aliases s_x
    {
        const f16x8* PB = (const f16x8*)Ph + (w * 32 + ln);
        f32x4 acc[2][2];
#pragma unroll
        for (int c = 0; c < 2; c++) { acc[c][0] = (f32x4){0,0,0,0}; acc[c][1] = (f32x4){0,0,0,0}; }
        f16x8 a0 = *(const f16x8*)&s_x[ln][q * 8];
        f16x8 a1 = *(const f16x8*)&s_x[16 + ln][q * 8];
        f16x8 bn[2];
#pragma unroll
        for (int c = 0; c < 2; c++) bn[c] = PB[(size_t)q * 128 + c * 16];
#pragma unroll
        for (int kk = 0; kk < 12; kk++) {
            f16x8 ca0 = a0, ca1 = a1;
            f16x8 bc[2];
#pragma unroll
            for (int c = 0; c < 2; c++) bc[c] = bn[c];
            if (kk < 11) {
                int kb = (kk + 1) * 4 + q;
#pragma unroll
                for (int c = 0; c < 2; c++) bn[c] = PB[(size_t)kb * 128 + c * 16];
                a0 = *(const f16x8*)&s_x[ln][(kk + 1) * 32 + q * 8];
                a1 = *(const f16x8*)&s_x[16 + ln][(kk + 1) * 32 + q * 8];
            }
#pragma unroll
            for (int c = 0; c < 2; c++) {
                acc[c][0] = __builtin_amdgcn_mfma_f32_16x16x32_f16(ca0, bc[c], acc[c][0], 0, 0, 0);
                acc[c][1] = __builtin_amdgcn_mfma_f32_16x16x32_f16(ca1, bc[c], acc[c][1], 0, 0, 0);
            }
        }
        float hv[2][2][4];
#pragma unroll
        for (int c = 0; c < 2; c++) {
            float bb = bh[w * 32 + c * 16 + ln];
#pragma unroll
            for (int rt = 0; rt < 2; rt++)
#pragma unroll
                for (int reg = 0; reg < 4; reg++)
                    hv[c][rt][reg] = conv3(acc[c][rt][reg] + bb, cw, cb);
        }
        __syncthreads();   // all s_x reads done before overwriting with s_hH
#pragma unroll
        for (int c = 0; c < 2; c++) {
            int colg = w * 32 + c * 16 + ln;
#pragma unroll
            for (int rt = 0; rt < 2; rt++)
#pragma unroll
                for (int reg = 0; reg < 4; reg++)
                    s_hH[rt * 16 + q * 4 + reg][colg] = (_Float16)hv[c][rt][reg];
        }
    }
    __syncthreads();

    // ---- Stage E: z = [h_H | hhu] @ Wz + bz; softmax gate; write out (N=512, K=512)
    {
        const f16x8* PBz = (const f16x8*)Pz + ln;
#pragma unroll
        for (int sub = 0; sub < 32; sub += 16) {
            int nc = w * 32 + sub;
            const f16x8* PL = PBz + nc;
            f32x4 acc[4][2];
#pragma unroll
            for (int q4 = 0; q4 < 4; q4++) { acc[q4][0] = (f32x4){0,0,0,0}; acc[q4][1] = (f32x4){0,0,0,0}; }
            f16x8 a0 = *(const f16x8*)&s_hH[ln][q * 8];
            f16x8 a1 = *(const f16x8*)&s_hH[16 + ln][q * 8];
            f16x8 bn[4];
#pragma unroll
            for (int q4 = 0; q4 < 4; q4++) bn[q4] = PL[(size_t)q * 512 + q4 * 128];
#pragma unroll
            for (int kk = 0; kk < 16; kk++) {
                f16x8 ca0 = a0, ca1 = a1;
                f16x8 bc[4];
#pragma unroll
                for (int q4 = 0; q4 < 4; q4++) bc[q4] = bn[q4];
                if (kk < 15) {
                    int kb = (kk + 1) * 4 + q;
#pragma unroll
                    for (int q4 = 0; q4 < 4; q4++) bn[q4] = PL[(size_t)kb * 512 + q4 * 128];
                    if (kk + 1 < 4) {
                        a0 = *(const f16x8*)&s_hH[ln][(kk + 1) * 32 + q * 8];
                        a1 = *(const f16x8*)&s_hH[16 + ln][(kk + 1) * 32 + q * 8];
                    } else {
                        int k0 = (kk + 1) * 32 - 128;
                        a0 = *(const f16x8*)&s_hhu[ln][k0 + q * 8];
                        a1 = *(const f16x8*)&s_hhu[16 + ln][k0 + q * 8];
                    }
                }
#pragma unroll
                for (int q4 = 0; q4 < 4; q4++) {
                    acc[q4][0] = __builtin_amdgcn_mfma_f32_16x16x32_f16(ca0, bc[q4], acc[q4][0], 0, 0, 0);
                    acc[q4][1] = __builtin_amdgcn_mfma_f32_16x16x32_f16(ca1, bc[q4], acc[q4][1], 0, 0, 0);
                }
            }
            int colg = nc + ln;
            float b0 = bz[colg], b1 = bz[128 + colg], b2 = bz[256 + colg], b3 = bz[384 + colg];
#pragma unroll
            for (int rt = 0; rt < 2; rt++)
#pragma unroll
                for (int reg = 0; reg < 4; reg++) {
                    int row = rt * 16 + q * 4 + reg;
                    float z0 = acc[0][rt][reg] + b0;
                    float z1 = acc[1][rt][reg] + b1;
                    float z2 = acc[2][rt][reg] + b2;
                    float z3 = acc[3][rt][reg] + b3;
                    float m = fmaxf(fmaxf(z0, z1), fmaxf(z2, z3));
                    float e0 = __expf(z0 - m), e1 = __expf(z1 - m), e2 = __expf(z2 - m), e3 = __expf(z3 - m);
                    float inv = 1.f / (e0 + e1 + e2 + e3);
                    float hH = (float)s_hH[row][colg];
                    float hL = (float)s_hhu[row][colg];
                    float hR = (float)s_hhu[row][128 + colg];
                    float uu = (float)s_hhu[row][256 + colg];
                    float e = (e0 * hH + e1 * hL + e2 * hR + e3 * uu) * inv;
                    size_t gidx = (size_t)(row0 + row) * H + colg;
                    if (finalOut) finalOut[gidx] = e;
                    else embOut[gidx] = (_Float16)e;
                }
        }
    }
}

extern "C" void kernel_launch(void* const* d_in, const int* in_sizes, int n_in,
                              void* d_out, int out_size, void* d_ws, size_t ws_size,
                              hipStream_t stream) {
    const float* contents = (const float*)d_in[0];
    const int*   children = (const int*)d_in[1];
    const float* Wu = (const float*)d_in[2];
    const float* bu = (const float*)d_in[3];
    const float* Wh = (const float*)d_in[4];
    const float* bh = (const float*)d_in[5];
    const float* Wz = (const float*)d_in[6];
    const float* bz = (const float*)d_in[7];
    const float* Wr = (const float*)d_in[8];
    const float* br = (const float*)d_in[9];
    const float* convw = (const float*)d_in[10];
    const float* convb = (const float*)d_in[11];
    float* out = (float*)d_out;

    // Workspace: [packed weights 1MB][bufA 64MB][bufB 64MB]
    _Float16* Pr = (_Float16*)d_ws;
    _Float16* Ph = Pr + 384 * 384;
    _Float16* Pz = Ph + 384 * 128;
    _Float16* bufA = (_Float16*)((char*)d_ws + (1 << 20));
    _Float16* bufB = bufA + (size_t)262144 * H;

    auto OFFS = [](int j) -> long long { return 1024LL * ((1LL << j) - 1); };

    pack_weights<<<(512 * 512 + 255) / 256, 256, 0, stream>>>(Wr, Wh, Wz, Pr, Ph, Pz);

    // Level 8 with fused leaf (level 9) computation
    {
        int n = 1024 << 8;
        level_kernel<true><<<n / ROWS, 256, 0, stream>>>(
            contents + OFFS(8) * FEAT, children + OFFS(8) * 2,
            contents + OFFS(9) * FEAT, nullptr, bufA, nullptr,
            Wu, bu, Pr, br, Ph, bh, Pz, bz, convw, convb);
    }

    _Float16* prev = bufA;
    _Float16* cur  = bufB;
    for (int j = 7; j >= 0; j--) {
        int n = 1024 << j;
        level_kernel<false><<<n / ROWS, 256, 0, stream>>>(
            contents + OFFS(j) * FEAT, children + OFFS(j) * 2,
            nullptr, prev, cur, (j == 0 ? out : nullptr),
            Wu, bu, Pr, br, Ph, bh, Pz, bz, convw, convb);
        _Float16* tmp = prev; prev = cur; cur = tmp;
    }
}